// Round 2
// baseline (269.189 us; speedup 1.0000x reference)
//
#include <hip/hip_runtime.h>

// Causal bag-of-words: out[b,t,c] = mean(x[b,0..t,c]).
// 3-phase chunked scan along T, fp32. B=8, T=8192, C=512 row-major.
//  k1: chunk sums (L=32) -> ws                      [reads x, 128 MiB]
//  k2: exclusive scan of chunk sums in-place in ws  [4 MiB, L2-resident]
//  k3: downsweep: run = ws[chunk]; stream chunk of x, divide, NT-store out.
// Occupancy: k1/k3 = 262144 threads = 4096 waves = 16 waves/CU.

typedef float v4f __attribute__((ext_vector_type(4)));

constexpr int B   = 8;
constexpr int T   = 8192;
constexpr int C   = 512;
constexpr int C4  = C / 4;     // 128
constexpr int L   = 32;        // chunk length along T
constexpr int NCH = T / L;     // 256 chunks
constexpr int NCOL = B * C4;   // 1024 scan columns
constexpr int NTHREAD = B * NCH * C4;  // 262144

__global__ __launch_bounds__(256, 4) void cbow_k1_chunksums(
        const v4f* __restrict__ x, v4f* __restrict__ ws) {
    const int tid   = blockIdx.x * 256 + threadIdx.x;
    const int c4    = tid & (C4 - 1);
    const int chunk = (tid >> 7) & (NCH - 1);
    const int b     = tid >> 15;          // tid / (C4*NCH)

    const v4f* p = x + (size_t)(b * T + chunk * L) * C4 + c4;
    v4f s = 0.f;
#pragma unroll 16
    for (int t = 0; t < L; ++t) s += p[t * C4];
    ws[(b * NCH + chunk) * C4 + c4] = s;
}

// One thread per (b,c4) column; consecutive tid -> consecutive c4 so each
// wave load is a contiguous 1 KiB segment. In-place exclusive scan.
__global__ __launch_bounds__(256) void cbow_k2_scan(v4f* __restrict__ ws) {
    const int col = blockIdx.x * 256 + threadIdx.x;   // [0, NCOL)
    const int b   = col >> 7;
    const int c4  = col & (C4 - 1);
    v4f* w = ws + (size_t)b * NCH * C4 + c4;
    v4f run = 0.f;
#pragma unroll 8
    for (int j = 0; j < NCH; ++j) {
        v4f v = w[(size_t)j * C4];
        w[(size_t)j * C4] = run;   // exclusive prefix
        run += v;
    }
}

__global__ __launch_bounds__(256, 4) void cbow_k3_downsweep(
        const v4f* __restrict__ x, const v4f* __restrict__ ws,
        v4f* __restrict__ out) {
    const int tid   = blockIdx.x * 256 + threadIdx.x;
    const int c4    = tid & (C4 - 1);
    const int chunk = (tid >> 7) & (NCH - 1);
    const int b     = tid >> 15;

    v4f run = ws[(b * NCH + chunk) * C4 + c4];   // sum of chunks < chunk
    const int    t0   = chunk * L;
    const size_t base = (size_t)(b * T + t0) * C4 + c4;
    const v4f* p = x + base;
    v4f*       o = out + base;
#pragma unroll 16
    for (int t = 0; t < L; ++t) {
        run += p[t * C4];
        const float inv = __builtin_amdgcn_rcpf((float)(t0 + t + 1));
        v4f r = run * inv;
        // NT store: keep x resident in L3 for k3's own later reads.
        __builtin_nontemporal_store(r, o + t * C4);
    }
}

extern "C" void kernel_launch(void* const* d_in, const int* in_sizes, int n_in,
                              void* d_out, int out_size, void* d_ws, size_t ws_size,
                              hipStream_t stream) {
    const v4f* x   = (const v4f*)d_in[0];
    v4f*       out = (v4f*)d_out;
    v4f*       ws  = (v4f*)d_ws;   // needs B*NCH*C4*16 = 4 MiB

    cbow_k1_chunksums<<<NTHREAD / 256, 256, 0, stream>>>(x, ws);
    cbow_k2_scan<<<NCOL / 256, 256, 0, stream>>>(ws);
    cbow_k3_downsweep<<<NTHREAD / 256, 256, 0, stream>>>(x, ws, out);
}